// Round 4
// baseline (1140.861 us; speedup 1.0000x reference)
//
#include <hip/hip_runtime.h>
#include <hip/hip_bf16.h>

// TriMipEncoding: x[800000,3] f32, fm[3,512,512,16] f32 -> out[800000,48] f32
//
// R4 = R3 with the compile fix: __builtin_nontemporal_load/store need native
// clang vectors, not HIP_vector_type. Entries use float4v ext_vector_type(4).
//
// Strategy recap: R2 showed FETCH ~= full gather demand (zero L2 hit; 25 MB
// fp16 texture thrashes the 4 MiB per-XCD L2 under uniform-random access).
// Bin (point,plane) gathers by 32x32-texel tile (768 bins), pin bins to XCDs
// (block%8 heuristic): per-XCD working set = 96 tiles ~= 3.3 MB < 4 MiB L2.

#define N_PTS   800000
#define PLANE   512
#define FDIM    16
#define FM_ELEMS (3 * PLANE * PLANE * FDIM)          // 12,582,912 floats
#define FMH_BYTES ((size_t)FM_ELEMS * 2)             // 25,165,824 B
#define UNITS   (N_PTS * 3)                          // 2,400,000
#define ENT_BYTES ((size_t)UNITS * 16)               // 38,400,000 B
#define NBINS   768                                  // 3 planes * 16*16 tiles
#define CTRL_BYTES 12288
#define WS_NEEDED (FMH_BYTES + ENT_BYTES + CTRL_BYTES)   // 63,578,112 B
#define GATHER_THREADS_R2 (N_PTS * 3 * 8)
#define TOTAL_F32 (N_PTS * 48)

typedef _Float16 half2v  __attribute__((ext_vector_type(2)));
typedef _Float16 half4v  __attribute__((ext_vector_type(4)));
typedef float    float2v __attribute__((ext_vector_type(2)));
typedef float    float4v __attribute__((ext_vector_type(4)));

// ---------------- pass 1: fm -> fp16 ----------------
__global__ __launch_bounds__(256) void convert_fp16_kernel(
    const float* __restrict__ fm, _Float16* __restrict__ fmh)
{
    unsigned t = blockIdx.x * blockDim.x + threadIdx.x;
    float4v v = ((const float4v*)fm)[t];
    half4v h;
    h.x = (_Float16)v.x; h.y = (_Float16)v.y;
    h.z = (_Float16)v.z; h.w = (_Float16)v.w;
    ((half4v*)fmh)[t] = h;
}

// ---------------- ctrl layout: counts[768], start[769], cursor[768] --------
__global__ __launch_bounds__(256) void zero_counts_kernel(unsigned* __restrict__ ctrl)
{
    unsigned t = threadIdx.x;
    ctrl[t] = 0; ctrl[t + 256] = 0; ctrl[t + 512] = 0;
}

__device__ __forceinline__ int bin_of(float a, float b, int p)
{
    float u = a * (float)PLANE - 0.5f;
    float v = b * (float)PLANE - 0.5f;
    int i0 = min(max((int)floorf(u), 0), PLANE - 1);
    int j0 = min(max((int)floorf(v), 0), PLANE - 1);
    return p * 256 + ((j0 >> 5) << 4) + (i0 >> 5);
}

// ---------------- pass 2: histogram ----------------
__global__ __launch_bounds__(256) void count_kernel(
    const float* __restrict__ x, unsigned* __restrict__ counts)
{
    unsigned n = blockIdx.x * blockDim.x + threadIdx.x;   // grid covers exactly N_PTS
    float x0 = x[3u * n + 0u];
    float x1 = x[3u * n + 1u];
    float x2 = x[3u * n + 2u];
#pragma unroll
    for (int p = 0; p < 3; ++p) {
        float a = (p == 0) ? x1 : x0;
        float b = (p == 2) ? x1 : x2;
        atomicAdd(&counts[bin_of(a, b, p)], 1u);
    }
}

// ---------------- pass 3: prefix sum over 768 bins (one block) -------------
__global__ __launch_bounds__(256) void scan_kernel(unsigned* __restrict__ ctrl)
{
    unsigned* counts = ctrl;
    unsigned* start  = ctrl + NBINS;          // 769 entries
    unsigned* cursor = ctrl + NBINS + NBINS + 1;
    __shared__ unsigned part[256];
    int t = threadIdx.x;
    unsigned c0 = counts[3 * t + 0];
    unsigned c1 = counts[3 * t + 1];
    unsigned c2 = counts[3 * t + 2];
    unsigned s = c0 + c1 + c2;
    part[t] = s;
    __syncthreads();
    for (int off = 1; off < 256; off <<= 1) {
        unsigned tmp = (t >= off) ? part[t - off] : 0u;
        __syncthreads();
        part[t] += tmp;
        __syncthreads();
    }
    unsigned base = part[t] - s;              // exclusive prefix
    start[3 * t + 0] = base;
    start[3 * t + 1] = base + c0;
    start[3 * t + 2] = base + c0 + c1;
    cursor[3 * t + 0] = base;
    cursor[3 * t + 1] = base + c0;
    cursor[3 * t + 2] = base + c0 + c1;
    if (t == 255) start[NBINS] = part[255];
}

// ---------------- pass 4: scatter entries into bin order -------------------
__global__ __launch_bounds__(256) void scatter_kernel(
    const float* __restrict__ x, unsigned* __restrict__ ctrl,
    float4v* __restrict__ ent)
{
    unsigned* cursor = ctrl + NBINS + NBINS + 1;
    unsigned n = blockIdx.x * blockDim.x + threadIdx.x;
    float x0 = x[3u * n + 0u];
    float x1 = x[3u * n + 1u];
    float x2 = x[3u * n + 2u];
#pragma unroll
    for (int p = 0; p < 3; ++p) {
        float a = (p == 0) ? x1 : x0;
        float b = (p == 2) ? x1 : x2;
        int bin = bin_of(a, b, p);
        unsigned pos = atomicAdd(&cursor[bin], 1u);
        float4v e;
        e.x = a; e.y = b;
        e.z = __uint_as_float(n | ((unsigned)p << 20));
        e.w = 0.0f;
        __builtin_nontemporal_store(e, &ent[pos]);
    }
}

// ---------------- pass 5: binned gather ----------------
// grid = 8 XCD * 96 bins * 8 chunks = 6144 blocks of 256
__global__ __launch_bounds__(256) void gather_binned_kernel(
    const float4v* __restrict__ ent,
    const unsigned* __restrict__ ctrl,
    const _Float16* __restrict__ fmh,
    float* __restrict__ out)
{
    const unsigned* start = ctrl + NBINS;
    unsigned xcd   = blockIdx.x & 7u;
    unsigned slot  = blockIdx.x >> 3;      // [0,768)
    unsigned binL  = slot % 96u;
    unsigned chunk = slot / 96u;           // [0,8)
    unsigned bin   = xcd * 96u + binL;

    unsigned lo  = start[bin];
    unsigned hi  = start[bin + 1];
    unsigned cnt = hi - lo;
    unsigned u0  = lo + (cnt * chunk) / 8u;
    unsigned u1  = lo + (cnt * (chunk + 1u)) / 8u;

    unsigned c2 = threadIdx.x & 7u;        // channel pair
    unsigned ub = threadIdx.x >> 3;        // unit within block iter [0,32)

    for (unsigned u = u0 + ub; u < u1; u += 32u) {
        float4v e = __builtin_nontemporal_load(&ent[u]);
        unsigned np = __float_as_uint(e.z);
        unsigned n  = np & 0xFFFFFu;
        unsigned p  = np >> 20;

        float uu = e.x * (float)PLANE - 0.5f;
        float vv = e.y * (float)PLANE - 0.5f;
        float i0f = floorf(uu);
        float j0f = floorf(vv);
        float fu = uu - i0f;
        float fv = vv - j0f;
        int i0 = (int)i0f;
        int j0 = (int)j0f;
        int i1 = min(max(i0 + 1, 0), PLANE - 1);
        int j1 = min(max(j0 + 1, 0), PLANE - 1);
        i0 = min(max(i0, 0), PLANE - 1);
        j0 = min(max(j0, 0), PLANE - 1);

        const _Float16* base = fmh + (size_t)p * (PLANE * PLANE * FDIM) + 2u * c2;
        half2v h00 = *(const half2v*)(base + (size_t)(j0 * PLANE + i0) * FDIM);
        half2v h01 = *(const half2v*)(base + (size_t)(j0 * PLANE + i1) * FDIM);
        half2v h10 = *(const half2v*)(base + (size_t)(j1 * PLANE + i0) * FDIM);
        half2v h11 = *(const half2v*)(base + (size_t)(j1 * PLANE + i1) * FDIM);

        float2v r;
        {
            float t00 = (float)h00.x, t01 = (float)h01.x;
            float t10 = (float)h10.x, t11 = (float)h11.x;
            float r0 = t00 + fu * (t01 - t00);
            float r1 = t10 + fu * (t11 - t10);
            r.x = r0 + fv * (r1 - r0);
        }
        {
            float t00 = (float)h00.y, t01 = (float)h01.y;
            float t10 = (float)h10.y, t11 = (float)h11.y;
            float r0 = t00 + fu * (t01 - t00);
            float r1 = t10 + fu * (t11 - t10);
            r.y = r0 + fv * (r1 - r0);
        }
        __builtin_nontemporal_store(r, &((float2v*)out)[(size_t)n * 24u + p * 8u + c2]);
    }
}

// ---------------- fallbacks (proven R2 / R1 kernels) ----------------
__global__ __launch_bounds__(256) void trimip_fp16_kernel(
    const float* __restrict__ x, const _Float16* __restrict__ fmh,
    float* __restrict__ out)
{
    unsigned t = blockIdx.x * blockDim.x + threadIdx.x;
    if (t >= (unsigned)GATHER_THREADS_R2) return;
    unsigned c2 = t & 7u, unit = t >> 3;
    unsigned n = unit / 3u, p = unit - n * 3u;
    unsigned iu = (p == 0u) ? 1u : 0u;
    unsigned iv = (p == 2u) ? 1u : 2u;
    float a = x[n * 3u + iu], b = x[n * 3u + iv];
    float u = a * (float)PLANE - 0.5f, v = b * (float)PLANE - 0.5f;
    float i0f = floorf(u), j0f = floorf(v);
    float fu = u - i0f, fv = v - j0f;
    int i0 = (int)i0f, j0 = (int)j0f;
    int i1 = min(max(i0 + 1, 0), PLANE - 1);
    int j1 = min(max(j0 + 1, 0), PLANE - 1);
    i0 = min(max(i0, 0), PLANE - 1);
    j0 = min(max(j0, 0), PLANE - 1);
    const _Float16* base = fmh + (size_t)p * (PLANE * PLANE * FDIM) + 2u * c2;
    half2v h00 = *(const half2v*)(base + (size_t)(j0 * PLANE + i0) * FDIM);
    half2v h01 = *(const half2v*)(base + (size_t)(j0 * PLANE + i1) * FDIM);
    half2v h10 = *(const half2v*)(base + (size_t)(j1 * PLANE + i0) * FDIM);
    half2v h11 = *(const half2v*)(base + (size_t)(j1 * PLANE + i1) * FDIM);
    float2v r;
    { float t00=(float)h00.x,t01=(float)h01.x,t10=(float)h10.x,t11=(float)h11.x;
      float r0=t00+fu*(t01-t00), r1=t10+fu*(t11-t10); r.x=r0+fv*(r1-r0); }
    { float t00=(float)h00.y,t01=(float)h01.y,t10=(float)h10.y,t11=(float)h11.y;
      float r0=t00+fu*(t01-t00), r1=t10+fu*(t11-t10); r.y=r0+fv*(r1-r0); }
    __builtin_nontemporal_store(r, &((float2v*)out)[t]);
}

__global__ __launch_bounds__(256) void trimip_f32_kernel(
    const float* __restrict__ x, const float* __restrict__ fm,
    float* __restrict__ out)
{
    unsigned t = blockIdx.x * blockDim.x + threadIdx.x;
    if (t >= (unsigned)TOTAL_F32) return;
    unsigned c = t & 15u, unit = t >> 4;
    unsigned n = unit / 3u, p = unit - n * 3u;
    unsigned iu = (p == 0u) ? 1u : 0u;
    unsigned iv = (p == 2u) ? 1u : 2u;
    float a = x[n * 3u + iu], b = x[n * 3u + iv];
    float u = a * (float)PLANE - 0.5f, v = b * (float)PLANE - 0.5f;
    float i0f = floorf(u), j0f = floorf(v);
    float fu = u - i0f, fv = v - j0f;
    int i0 = (int)i0f, j0 = (int)j0f;
    int i1 = min(max(i0 + 1, 0), PLANE - 1);
    int j1 = min(max(j0 + 1, 0), PLANE - 1);
    i0 = min(max(i0, 0), PLANE - 1);
    j0 = min(max(j0, 0), PLANE - 1);
    const float* base = fm + (size_t)p * (PLANE * PLANE * FDIM);
    float t00 = base[((size_t)(j0 * PLANE + i0)) * FDIM + c];
    float t01 = base[((size_t)(j0 * PLANE + i1)) * FDIM + c];
    float t10 = base[((size_t)(j1 * PLANE + i0)) * FDIM + c];
    float t11 = base[((size_t)(j1 * PLANE + i1)) * FDIM + c];
    float r0 = t00 + fu * (t01 - t00);
    float r1 = t10 + fu * (t11 - t10);
    float r  = r0 + fv * (r1 - r0);
    __builtin_nontemporal_store(r, &out[t]);
}

extern "C" void kernel_launch(void* const* d_in, const int* in_sizes, int n_in,
                              void* d_out, int out_size, void* d_ws, size_t ws_size,
                              hipStream_t stream)
{
    const float* x  = (const float*)d_in[0];
    const float* fm = (const float*)d_in[1];
    float* out      = (float*)d_out;

    if (ws_size >= WS_NEEDED) {
        _Float16* fmh = (_Float16*)d_ws;
        float4v*  ent = (float4v*)((char*)d_ws + FMH_BYTES);
        unsigned* ctrl = (unsigned*)((char*)d_ws + FMH_BYTES + ENT_BYTES);

        convert_fp16_kernel<<<FM_ELEMS / 4 / 256, 256, 0, stream>>>(fm, fmh);
        zero_counts_kernel<<<1, 256, 0, stream>>>(ctrl);
        count_kernel<<<N_PTS / 256, 256, 0, stream>>>(x, ctrl);
        scan_kernel<<<1, 256, 0, stream>>>(ctrl);
        scatter_kernel<<<N_PTS / 256, 256, 0, stream>>>(x, ctrl, ent);
        gather_binned_kernel<<<8 * 96 * 8, 256, 0, stream>>>(ent, ctrl, fmh, out);
    } else if (ws_size >= FMH_BYTES) {
        _Float16* fmh = (_Float16*)d_ws;
        convert_fp16_kernel<<<FM_ELEMS / 4 / 256, 256, 0, stream>>>(fm, fmh);
        trimip_fp16_kernel<<<GATHER_THREADS_R2 / 256, 256, 0, stream>>>(x, fmh, out);
    } else {
        trimip_f32_kernel<<<(TOTAL_F32 + 255) / 256, 256, 0, stream>>>(x, fm, out);
    }
}